// Round 10
// baseline (463.216 us; speedup 1.0000x reference)
//
#include <hip/hip_runtime.h>
#include <hip/hip_bf16.h>
#include <stdint.h>

// NonLocalBlock. Inputs/outputs FLOAT32; bf16 internal. B=16, C=512, N=4096.
// R14: gram latency round (R13 + three co-designed gram changes).
//  - T1 XCD swizzle (bijective, 160=8x20): each XCD owns 2 batches -> panel
//    reuse lands in its own L2 (fetch was 131 MB vs 67 ideal; loads at HBM
//    latency). w = (flat%8)*20 + flat/8; b = w/10, tl = w%10.
//  - BK=64: 32 MFMA + 8 DMAs per barrier (2x compute density per latency
//    window), 64 iters. LDS 3 bufs x 2 panels x 16 KB = 96 KB.
//  - Bank swizzle for 128B rows: physical chunk p of row r holds data chunk
//    p^(r&7) (else fr drops out of bank index -> 16-way conflict). Read-side
//    XOR folds to per-lane constants (wm+i*16 = 0 mod 8).
//  - All other kernels byte-identical to R13 (passing, 453.6 us).

typedef unsigned short u16;
typedef __attribute__((ext_vector_type(8))) short frag8;   // 8 bf16 = 4 VGPRs
typedef __attribute__((ext_vector_type(4))) float f32x4;

__device__ __forceinline__ u16 f2bf(float f) {
  union { __hip_bfloat16 h; u16 u; } c; c.h = __float2bfloat16(f); return c.u;
}

// async global->LDS DMA, 16B per lane. LDS dest must be wave-uniform base +
// lane*16 — all call sites use (shared_base + tid*8 u16) which satisfies this.
__device__ __forceinline__ void gl_lds16(const u16* g, u16* l) {
  __builtin_amdgcn_global_load_lds(
      (const __attribute__((address_space(1))) void*)g,
      (__attribute__((address_space(3))) void*)l, 16, 0, 0);
}

#define SCHED0 __builtin_amdgcn_sched_barrier(0)
#define SBAR   __builtin_amdgcn_s_barrier()

// ---------------- prep_x: x f32 -> xT bf16, xb bf16, S rowsums ----------------
__global__ __launch_bounds__(256) void prep_x(const float* __restrict__ X,
                                              u16* __restrict__ XT,
                                              u16* __restrict__ XB,
                                              float* __restrict__ S) {
  const int b = blockIdx.z;
  const int n0 = blockIdx.x * 64;
  const int c0 = blockIdx.y * 64;
  __shared__ u16 t[64][72];
  const float* Xb = X + (int64_t)b * (512LL * 4096);
  const int tid = threadIdx.x;
  const int r = tid >> 3;        // 0..31
  const int e8 = (tid & 7) * 8;  // 0..56
#pragma unroll
  for (int p = 0; p < 2; p++) {
    const int row = p * 32 + r;
    const int c = c0 + row;
    const float4 f0 = *(const float4*)(Xb + (int64_t)c * 4096 + n0 + e8);
    const float4 f1 = *(const float4*)(Xb + (int64_t)c * 4096 + n0 + e8 + 4);
    union { uint4 q; u16 u[8]; } pk;
    pk.u[0] = f2bf(f0.x); pk.u[1] = f2bf(f0.y); pk.u[2] = f2bf(f0.z); pk.u[3] = f2bf(f0.w);
    pk.u[4] = f2bf(f1.x); pk.u[5] = f2bf(f1.y); pk.u[6] = f2bf(f1.z); pk.u[7] = f2bf(f1.w);
    *(uint4*)(XB + ((int64_t)b * 512 + c) * 4096 + n0 + e8) = pk.q;
    // XOR-swizzle: logical col c' of row stored at c' ^ (row & 56).
    *(uint4*)&t[row][e8 ^ (row & 56)] = pk.q;
    float s = f0.x + f0.y + f0.z + f0.w + f1.x + f1.y + f1.z + f1.w;
    s += __shfl_xor(s, 1); s += __shfl_xor(s, 2); s += __shfl_xor(s, 4);
    if ((tid & 7) == 0) atomicAdd(&S[b * 512 + c], s);
  }
  __syncthreads();
#pragma unroll
  for (int p = 0; p < 2; p++) {
    const int nr = p * 32 + r;
    union { uint4 q; u16 u[8]; } o;
#pragma unroll
    for (int j = 0; j < 8; j++)
      o.u[j] = t[e8 + j][nr ^ e8];  // (e8+j)&56 == e8 since j<8, e8%8==0
    *(uint4*)(XT + ((int64_t)b * 4096 + n0 + nr) * 512 + c0 + e8) = o.q;
  }
}

// ------- gram, no split-K, BK=64, XCD-swizzled: G_b = XB_b XB_b^T -------
__constant__ const int g_ty[10] = {0,0,0,0,1,1,1,2,2,3};
__constant__ const int g_tx[10] = {0,1,2,3,1,2,3,2,3,3};

__global__ __launch_bounds__(256) void gram_sk(const u16* __restrict__ XB,
                                               u16* __restrict__ G) {
  // bijective XCD swizzle: 160 blocks = 8 XCDs x 20; XCD x owns b = 2x, 2x+1.
  const int flat = blockIdx.x;
  const int w = (flat & 7) * 20 + (flat >> 3);
  const int b = w / 10;
  const int tl = w - b * 10;             // 0..9 upper-triangle tile
  const int m0 = g_ty[tl] * 128, n0 = g_tx[tl] * 128;
  const int tid = threadIdx.x;
  const int lane = tid & 63, wave = tid >> 6;
  __shared__ u16 sA[3][8192];            // 3 bufs x [128][64] bf16 = 48 KB
  __shared__ u16 sB[3][8192];
  const u16* Xb = XB + (int64_t)b * (512LL * 4096);

  f32x4 acc[4][4];
#pragma unroll
  for (int i = 0; i < 4; i++)
#pragma unroll
    for (int j = 0; j < 4; j++)
#pragma unroll
      for (int r = 0; r < 4; r++) acc[i][j][r] = 0.0f;

  const int fr = lane & 15;
  const int hi = lane >> 4;
  // 128B-row bank swizzle: physical chunk p of row r = data chunk p^(r&7).
  // Read chunks (data) kk*4+hi at row wm+i*16+fr -> physical (kk*4+hi)^(fr&7).
  const int fkx0 = ((hi) ^ (fr & 7)) * 8;
  const int fkx1 = ((4 + hi) ^ (fr & 7)) * 8;
  const int wm = (wave & 1) * 64, wn = (wave >> 1) * 64;

  // staging: DMA d covers rows d*32..d*32+31; thread row = d*32 + tid>>3,
  // physical chunk tid&7 -> source data chunk (tid&7)^((tid>>3)&7).
  const int srow = tid >> 3;             // 0..31
  const int scol = (((tid & 7) ^ ((tid >> 3) & 7))) * 8;
  const u16* ArA = Xb + (int64_t)(m0 + srow) * 4096 + scol;
  const u16* BrA = Xb + (int64_t)(n0 + srow) * 4096 + scol;

  auto stage = [&](int t, int buf) {   // 8 DMAs per tile (BK=64)
    const u16* a = ArA + t * 64;
    const u16* bb = BrA + t * 64;
#pragma unroll
    for (int d = 0; d < 4; d++) {
      gl_lds16(a + (int64_t)d * (32 * 4096), sA[buf] + d * 2048 + tid * 8);
      gl_lds16(bb + (int64_t)d * (32 * 4096), sB[buf] + d * 2048 + tid * 8);
    }
  };
  auto comp = [&](int buf) {
#pragma unroll
    for (int kk = 0; kk < 2; kk++) {
      const int fx = kk ? fkx1 : fkx0;
      frag8 af[4], bf[4];
#pragma unroll
      for (int i = 0; i < 4; i++) {
        af[i] = *(const frag8*)(sA[buf] + (wm + i * 16 + fr) * 64 + fx);
        bf[i] = *(const frag8*)(sB[buf] + (wn + i * 16 + fr) * 64 + fx);
      }
#pragma unroll
      for (int i = 0; i < 4; i++)
#pragma unroll
        for (int j = 0; j < 4; j++)
          acc[i][j] = __builtin_amdgcn_mfma_f32_16x16x32_bf16(af[i], bf[j], acc[i][j], 0, 0, 0);
    }
  };

  stage(0, 0); stage(1, 1);            // NT=64 K-tiles (K=4096, BK=64)
  for (int t = 0; t < 62; t++) {
    SCHED0; SBAR; SCHED0;              // buf[(t+2)%3] free (read at iter t-1)
    stage(t + 2, (t + 2) % 3);
    asm volatile("s_waitcnt vmcnt(16)" ::: "memory");  // tile t landed (16 newer)
    SBAR; SCHED0;                      // cross-wave: all tile-t DMAs landed
    comp(t % 3);
  }
  asm volatile("s_waitcnt vmcnt(0)" ::: "memory");
  SBAR; SCHED0;
  comp(62 % 3); comp(63 % 3);

  u16* Gb = G + (int64_t)b * 262144;
  const int quad = lane >> 4;
#pragma unroll
  for (int i = 0; i < 4; i++)
#pragma unroll
    for (int j = 0; j < 4; j++) {
      const int row0 = m0 + wm + i * 16 + quad * 4;
      const int col = n0 + wn + j * 16 + fr;
      union { u16 u[4]; uint2 v; } mg;
#pragma unroll
      for (int r = 0; r < 4; r++) {
        const u16 h = f2bf(acc[i][j][r]);
        Gb[(int64_t)(row0 + r) * 512 + col] = h;
        mg.u[r] = h;
      }
      if (m0 != n0)  // mirror (4 contiguous bf16 = 8B store)
        *(uint2*)(Gb + (int64_t)col * 512 + row0) = mg.v;
    }
}

// ------ 128x128-tile bt GEMM, K=512, 4 waves, depth-3 counted pipeline ------
enum { EPI_BF16 = 0, EPI_SCORES = 1, EPI_BF16I = 2 };

template <int EPI>
__global__ __launch_bounds__(256) void gemm128_bt(
    const u16* __restrict__ A, int64_t sAb, int lda,
    const u16* __restrict__ B, int64_t sBb, int ldb,
    void* __restrict__ Cv, int64_t sCb, int ldc,
    const float* __restrict__ e_bphi, const float* __restrict__ e_btheta,
    const float* __restrict__ e_uphi, const float* __restrict__ e_utheta) {
  const int b = blockIdx.z;
  const int m0 = blockIdx.y * 128, n0 = blockIdx.x * 128;
  const int tid = threadIdx.x;
  const int lane = tid & 63, wave = tid >> 6;
  __shared__ u16 sA[4][4096];
  __shared__ u16 sB[4][4096];
  const u16* Ab = A + (int64_t)b * sAb;
  const u16* Bb = B + (int64_t)b * sBb;

  f32x4 acc[4][4];
#pragma unroll
  for (int i = 0; i < 4; i++)
#pragma unroll
    for (int j = 0; j < 4; j++)
#pragma unroll
      for (int r = 0; r < 4; r++) acc[i][j][r] = 0.0f;

  const int srow = tid >> 2;           // 0..63
  const int scol = (((tid & 3) ^ ((tid >> 3) & 3))) * 8;  // pre-swizzled source
  const int fr = lane & 15;
  const int fkx = (((lane >> 4) ^ ((fr >> 1) & 3))) * 8;  // swizzled read chunk
  const int wm = (wave & 1) * 64, wn = (wave >> 1) * 64;

  const u16* Ar0 = Ab + (int64_t)(m0 + srow) * lda + scol;
  const u16* Ar1 = Ab + (int64_t)(m0 + 64 + srow) * lda + scol;
  const u16* Br0 = Bb + (int64_t)(n0 + srow) * ldb + scol;
  const u16* Br1 = Bb + (int64_t)(n0 + 64 + srow) * ldb + scol;

  auto stage = [&](int t, int buf) {   // 4 DMAs per tile
    gl_lds16(Ar0 + t * 32, sA[buf] + tid * 8);
    gl_lds16(Ar1 + t * 32, sA[buf] + 2048 + tid * 8);
    gl_lds16(Br0 + t * 32, sB[buf] + tid * 8);
    gl_lds16(Br1 + t * 32, sB[buf] + 2048 + tid * 8);
  };
  auto comp = [&](int buf) {
    frag8 af[4], bf[4];
#pragma unroll
    for (int i = 0; i < 4; i++) {
      af[i] = *(const frag8*)(sA[buf] + (wm + i * 16 + fr) * 32 + fkx);
      bf[i] = *(const frag8*)(sB[buf] + (wn + i * 16 + fr) * 32 + fkx);
    }
#pragma unroll
    for (int i = 0; i < 4; i++)
#pragma unroll
      for (int j = 0; j < 4; j++)
        acc[i][j] = __builtin_amdgcn_mfma_f32_16x16x32_bf16(af[i], bf[j], acc[i][j], 0, 0, 0);
  };

  stage(0, 0); stage(1, 1); stage(2, 2);   // NT=16 K-tiles, depth-3
#pragma unroll
  for (int t = 0; t < 13; t++) {
    SCHED0; SBAR; SCHED0;              // buf[(t+3)%4] free (read at iter t-1)
    stage(t + 3, (t + 3) % 4);
    asm volatile("s_waitcnt vmcnt(12)" ::: "memory");  // tile t landed (12 newer)
    SBAR; SCHED0;                      // cross-wave visibility
    comp(t % 4);
  }
  asm volatile("s_waitcnt vmcnt(8)" ::: "memory");
  SBAR; SCHED0;
  comp(13 % 4);
  asm volatile("s_waitcnt vmcnt(4)" ::: "memory");
  SBAR; SCHED0;
  comp(14 % 4);
  asm volatile("s_waitcnt vmcnt(0)" ::: "memory");
  SBAR; SCHED0;
  comp(15 % 4);

  const int quad = lane >> 4;
#pragma unroll
  for (int i = 0; i < 4; i++)
#pragma unroll
    for (int j = 0; j < 4; j++)
#pragma unroll
      for (int r = 0; r < 4; r++) {
        const int row = m0 + wm + i * 16 + quad * 4 + r;
        const int col = n0 + wn + j * 16 + fr;
        const float a = acc[i][j][r];
        if constexpr (EPI == EPI_BF16) {
          ((u16*)Cv)[(int64_t)b * sCb + (int64_t)row * ldc + col] = f2bf(a);
        } else if constexpr (EPI == EPI_BF16I) {
          ((u16*)Cv)[(int64_t)b * sCb + (int64_t)row * ldc + col] =
              f2bf(a + (row == col ? 1.0f : 0.0f));
        } else {  // EPI_SCORES
          const float bp = e_bphi[row];
          const float bt = e_btheta[col];
          ((float*)Cv)[(int64_t)b * sCb + (int64_t)row * ldc + col] =
              (a + bp * e_utheta[b * 512 + col] + bt * e_uphi[b * 512 + row] +
               4096.0f * bp * bt) * (1.0f / 512.0f);
        }
      }
}

// ---------------- final: out f32 = (M+I) x + v (A=M bf16, B=xT) ----------------
// 2-buffer, one __syncthreads per iter (measured faster than counted).
__global__ __launch_bounds__(256) void gemm_final(const u16* __restrict__ M,
                                                  const u16* __restrict__ XT,
                                                  const float* __restrict__ V,
                                                  float* __restrict__ O) {
  const int b = blockIdx.z;
  const int m0 = blockIdx.y * 128, n0 = blockIdx.x * 128;
  const int tid = threadIdx.x;
  const int lane = tid & 63, wave = tid >> 6;
  __shared__ u16 sA[2][4096];
  __shared__ u16 sB[2][4096];
  const u16* Ab = M + (int64_t)b * 262144;
  const u16* Bb = XT + (int64_t)b * (4096LL * 512);

  f32x4 acc[4][4];
#pragma unroll
  for (int i = 0; i < 4; i++)
#pragma unroll
    for (int j = 0; j < 4; j++)
#pragma unroll
      for (int r = 0; r < 4; r++) acc[i][j][r] = 0.0f;

  const int srow = tid >> 2;
  const int scol = (((tid & 3) ^ ((tid >> 3) & 3))) * 8;  // pre-swizzled source
  const int fr = lane & 15;
  const int fkx = (((lane >> 4) ^ ((fr >> 1) & 3))) * 8;  // swizzled read chunk
  const int wm = (wave & 1) * 64, wn = (wave >> 1) * 64;

  const u16* Ar0 = Ab + (int64_t)(m0 + srow) * 512 + scol;
  const u16* Ar1 = Ab + (int64_t)(m0 + 64 + srow) * 512 + scol;
  const u16* Br0 = Bb + (int64_t)(n0 + srow) * 512 + scol;
  const u16* Br1 = Bb + (int64_t)(n0 + 64 + srow) * 512 + scol;

  // prologue
  gl_lds16(Ar0, sA[0] + tid * 8);
  gl_lds16(Ar1, sA[0] + 2048 + tid * 8);
  gl_lds16(Br0, sB[0] + tid * 8);
  gl_lds16(Br1, sB[0] + 2048 + tid * 8);
  __syncthreads();

  for (int k0 = 0; k0 < 512; k0 += 32) {
    const int cur = (k0 >> 5) & 1;
    if (k0 + 32 < 512) {
      u16* dA = sA[cur ^ 1];
      u16* dB = sB[cur ^ 1];
      gl_lds16(Ar0 + k0 + 32, dA + tid * 8);
      gl_lds16(Ar1 + k0 + 32, dA + 2048 + tid * 8);
      gl_lds16(Br0 + k0 + 32, dB + tid * 8);
      gl_lds16(Br1 + k0 + 32, dB + 2048 + tid * 8);
    }
    frag8 af[4], bf[4];
#pragma unroll
    for (int i = 0; i < 4; i++) {
      af[i] = *(const frag8*)(sA[cur] + (wm + i * 16 + fr) * 32 + fkx);
      bf[i] = *(const frag8*)(sB[cur] + (wn + i * 16 + fr) * 32 + fkx);
    }
#pragma unroll
    for (int i = 0; i < 4; i++)
#pragma unroll
      for (int j = 0; j < 4; j++)
        acc[i][j] = __builtin_amdgcn_mfma_f32_16x16x32_bf16(af[i], bf[j], acc[i][j], 0, 0, 0);
    __syncthreads();
  }

  const int quad = lane >> 4;
#pragma unroll
  for (int i = 0; i < 4; i++)
#pragma unroll
    for (int j = 0; j < 4; j++)
#pragma unroll
      for (int r = 0; r < 4; r++) {
        const int row = m0 + wm + i * 16 + quad * 4 + r;
        const int col = n0 + wn + j * 16 + fr;
        O[(int64_t)b * (512LL * 4096) + (int64_t)row * 4096 + col] =
            acc[i][j][r] + V[b * 512 + row];
      }
}

// ---------------- small helpers ----------------
// uv: grid (16, 8), 256 threads; 4 lanes per output row, shfl reduce.
__global__ __launch_bounds__(256) void uv_kernel(const float* __restrict__ Wphi,
                                                 const float* __restrict__ Wtheta,
                                                 const float* __restrict__ S,
                                                 float* __restrict__ UPH, float* __restrict__ UTH) {
  const int b = blockIdx.x;
  const int o0 = blockIdx.y * 64;
  const int tid = threadIdx.x;
  __shared__ float s[512];
  s[tid] = S[b * 512 + tid];
  s[tid + 256] = S[b * 512 + tid + 256];
  __syncthreads();
  const int o = o0 + (tid >> 2);
  const int q = tid & 3;
  float a0 = 0.f, a1 = 0.f;
  for (int c = q * 128; c < q * 128 + 128; c += 4) {
    const float4 wa = *(const float4*)(Wphi + (int64_t)o * 512 + c);
    const float4 wb = *(const float4*)(Wtheta + (int64_t)o * 512 + c);
    a0 += wa.x * s[c] + wa.y * s[c + 1] + wa.z * s[c + 2] + wa.w * s[c + 3];
    a1 += wb.x * s[c] + wb.y * s[c + 1] + wb.z * s[c + 2] + wb.w * s[c + 3];
  }
  a0 += __shfl_xor(a0, 1); a0 += __shfl_xor(a0, 2);
  a1 += __shfl_xor(a1, 1); a1 += __shfl_xor(a1, 2);
  if (q == 0) {
    UPH[b * 512 + o] = a0;
    UTH[b * 512 + o] = a1;
  }
}

// v: grid (16, 8), same structure.
__global__ __launch_bounds__(256) void v_kernel(const float* __restrict__ Wout,
                                                const float* __restrict__ R,
                                                const float* __restrict__ bout,
                                                float* __restrict__ V) {
  const int b = blockIdx.x;
  const int o0 = blockIdx.y * 64;
  const int tid = threadIdx.x;
  __shared__ float s[512];
  s[tid] = R[b * 512 + tid];
  s[tid + 256] = R[b * 512 + tid + 256];
  __syncthreads();
  const int o = o0 + (tid >> 2);
  const int q = tid & 3;
  float a0 = 0.f;
  for (int c = q * 128; c < q * 128 + 128; c += 4) {
    const float4 wa = *(const float4*)(Wout + (int64_t)o * 512 + c);
    a0 += wa.x * s[c] + wa.y * s[c + 1] + wa.z * s[c + 2] + wa.w * s[c + 3];
  }
  a0 += __shfl_xor(a0, 1); a0 += __shfl_xor(a0, 2);
  if (q == 0) V[b * 512 + o] = a0 + bout[o];
}

__global__ __launch_bounds__(256) void convert_w(const float* __restrict__ W0,
                                                 const float* __restrict__ W1,
                                                 const float* __restrict__ W2,
                                                 u16* __restrict__ O0, u16* __restrict__ O1,
                                                 u16* __restrict__ O2) {
  const int idx = blockIdx.x * 256 + threadIdx.x;
  const int m = idx >> 16;
  const int off = (idx & 65535) * 4;
  const float* src = (m == 0) ? W0 : (m == 1) ? W1 : W2;
  u16* dst = (m == 0) ? O0 : (m == 1) ? O1 : O2;
  const float4 f = *(const float4*)(src + off);
  union { u16 u[4]; uint2 v; } p;
  p.u[0] = f2bf(f.x); p.u[1] = f2bf(f.y); p.u[2] = f2bf(f.z); p.u[3] = f2bf(f.w);
  *(uint2*)(dst + off) = p.v;
}

__global__ void wg_transpose(const float* __restrict__ Wg, u16* __restrict__ WgT) {
  __shared__ float t[16][17];
  const int i0 = blockIdx.y * 16, j0 = blockIdx.x * 16;
  t[threadIdx.y][threadIdx.x] = Wg[(i0 + threadIdx.y) * 512 + j0 + threadIdx.x];
  __syncthreads();
  WgT[(j0 + threadIdx.y) * 512 + i0 + threadIdx.x] = f2bf(t[threadIdx.x][threadIdx.y]);
}

__global__ __launch_bounds__(64) void softmax_k(float* __restrict__ SC,
                                                const float* __restrict__ bg,
                                                float* __restrict__ R) {
  const int row = blockIdx.x;
  const int lane = threadIdx.x;
  float* Sr = SC + (int64_t)row * 512;
  union { float4 q[2]; float v[8]; } u;
  u.q[0] = *(const float4*)(Sr + lane * 8);
  u.q[1] = *(const float4*)(Sr + lane * 8 + 4);
  const float4 g0 = *(const float4*)(bg + lane * 8);
  const float4 g1 = *(const float4*)(bg + lane * 8 + 4);
  const float gb[8] = { g0.x, g0.y, g0.z, g0.w, g1.x, g1.y, g1.z, g1.w };
  float m = u.v[0];
#pragma unroll
  for (int j = 1; j < 8; j++) m = fmaxf(m, u.v[j]);
#pragma unroll
  for (int off = 32; off > 0; off >>= 1) m = fmaxf(m, __shfl_xor(m, off));
  float e[8], s = 0.f, sb = 0.f;
#pragma unroll
  for (int j = 0; j < 8; j++) {
    e[j] = __expf(u.v[j] - m);
    s += e[j];
    sb += e[j] * gb[j];
  }
#pragma unroll
  for (int off = 32; off > 0; off >>= 1) { s += __shfl_xor(s, off); sb += __shfl_xor(sb, off); }
  const float inv = 1.0f / s;
  union { uint4 q; u16 h[8]; } o;
#pragma unroll
  for (int j = 0; j < 8; j++) o.h[j] = f2bf(e[j] * inv);
  *(uint4*)((u16*)SC + (int64_t)row * 1024 + lane * 8) = o.q;  // attn in-place
  if (lane == 0) R[row] = sb * inv;
}

extern "C" void kernel_launch(void* const* d_in, const int* in_sizes, int n_in,
                              void* d_out, int out_size, void* d_ws, size_t ws_size,
                              hipStream_t stream) {
  const float* x      = (const float*)d_in[0];
  const float* Wtheta = (const float*)d_in[1];
  const float* btheta = (const float*)d_in[2];
  const float* Wphi   = (const float*)d_in[3];
  const float* bphi   = (const float*)d_in[4];
  const float* Wg     = (const float*)d_in[5];
  const float* bg     = (const float*)d_in[6];
  const float* Wout   = (const float*)d_in[7];
  const float* bout   = (const float*)d_in[8];

  char* ws = (char*)d_ws;                   // ~98.1 MiB (same as proven R3 budget)
  u16*   xT     = (u16*)(ws + 0);           // 67,108,864
  u16*   G      = (u16*)(ws + 67108864);    //  8,388,608
  u16*   T1     = (u16*)(ws + 75497472);    //  8,388,608
  float* SC     = (float*)(ws + 83886080);  // 16,777,216 (attn bf16 in-place)
  u16*   Wphib  = (u16*)(ws + 100663296);
  u16*   Wthetab= (u16*)(ws + 101187584);
  u16*   Woutb  = (u16*)(ws + 101711872);
  u16*   WgTb   = (u16*)(ws + 102236160);
  float* S      = (float*)(ws + 102760448);
  float* UPH    = (float*)(ws + 102793216);
  float* UTH    = (float*)(ws + 102825984);
  float* R      = (float*)(ws + 102858752);
  float* V      = (float*)(ws + 102891520);
  u16* ATT = (u16*)SC;  // bf16 attn, row stride 1024 u16
  u16* Q = G;           // G dead after T1-gemm
  u16* M = T1;          // T1 dead after scores-gemm

  // d_out (134,217,728 B) as mid-pipeline scratch; fully overwritten by gemm_final.
  u16*   XB = (u16*)d_out;                          // 67,108,864: bf16 x

  hipMemsetAsync(S, 0, 32768, stream);
  prep_x<<<dim3(64, 8, 16), 256, 0, stream>>>(x, xT, XB, S);
  uv_kernel<<<dim3(16, 8), 256, 0, stream>>>(Wphi, Wtheta, S, UPH, UTH);
  convert_w<<<768, 256, 0, stream>>>(Wphi, Wtheta, Wout, Wphib, Wthetab, Woutb);
  wg_transpose<<<dim3(32, 32), dim3(16, 16), 0, stream>>>(Wg, WgTb);
  // G_b = XB_b XB_b^T directly in bf16 (no split-K partials, no reduce)
  gram_sk<<<dim3(160), 256, 0, stream>>>(XB, G);
  // T1_b = Wphi G_b (G symmetric -> bt form valid)
  gemm128_bt<EPI_BF16><<<dim3(4, 4, 16), 256, 0, stream>>>(
      Wphib, 0, 512, G, 512LL * 512, 512, T1, 512LL * 512, 512,
      nullptr, nullptr, nullptr, nullptr);
  // scores_b = (T1 Wtheta^T + rank-1 terms) / 512
  gemm128_bt<EPI_SCORES><<<dim3(4, 4, 16), 256, 0, stream>>>(
      T1, 512LL * 512, 512, Wthetab, 0, 512, SC, 512LL * 512, 512,
      bphi, btheta, UPH, UTH);
  softmax_k<<<8192, 64, 0, stream>>>(SC, bg, R);
  // Q_b[j,c] = sum_d WgT[j,d] attn[c,d]
  gemm128_bt<EPI_BF16><<<dim3(4, 4, 16), 256, 0, stream>>>(
      WgTb, 0, 512, ATT, 512LL * 1024, 1024, Q, 512LL * 512, 512,
      nullptr, nullptr, nullptr, nullptr);
  // M_b = Wout Q (+ I fold for the residual)
  gemm128_bt<EPI_BF16I><<<dim3(4, 4, 16), 256, 0, stream>>>(
      Woutb, 0, 512, Q, 512LL * 512, 512, M, 512LL * 512, 512,
      nullptr, nullptr, nullptr, nullptr);
  v_kernel<<<dim3(16, 8), 256, 0, stream>>>(Wout, R, bout, V);
  // out = (M+I) x + v  (reads xT + M only; overwrites all of d_out)
  gemm_final<<<dim3(32, 4, 16), 256, 0, stream>>>(M, xT, V, (float*)d_out);
}

// Round 11
// 446.213 us; speedup vs baseline: 1.0381x; 1.0381x over previous
//
#include <hip/hip_runtime.h>
#include <hip/hip_bf16.h>
#include <stdint.h>

// NonLocalBlock. Inputs/outputs FLOAT32; bf16 internal. B=16, C=512, N=4096.
// R15: latency round.
//  - prep_x: hoist all 4 float4 loads before converts (2x in-flight loads;
//    kernel is 2x off BW roofline at VALUBusy 6% = latency-bound).
//  - gemm_final: bijective XCD swizzle (2048=8x256; each XCD owns 2 batches,
//    y-sweeps re-read the same 4MB xT slice from own L2). FETCH already
//    ideal -> this targets latency (L3-hit -> L2-hit), per m192.
//  - gemm128_bt: same swizzle (256=8x32), per-b operands L2-resident.
//  - gram_sk (R14 form), softmax, helpers unchanged.

typedef unsigned short u16;
typedef __attribute__((ext_vector_type(8))) short frag8;   // 8 bf16 = 4 VGPRs
typedef __attribute__((ext_vector_type(4))) float f32x4;

__device__ __forceinline__ u16 f2bf(float f) {
  union { __hip_bfloat16 h; u16 u; } c; c.h = __float2bfloat16(f); return c.u;
}

// async global->LDS DMA, 16B per lane. LDS dest must be wave-uniform base +
// lane*16 — all call sites use (shared_base + tid*8 u16) which satisfies this.
__device__ __forceinline__ void gl_lds16(const u16* g, u16* l) {
  __builtin_amdgcn_global_load_lds(
      (const __attribute__((address_space(1))) void*)g,
      (__attribute__((address_space(3))) void*)l, 16, 0, 0);
}

#define SCHED0 __builtin_amdgcn_sched_barrier(0)
#define SBAR   __builtin_amdgcn_s_barrier()

// ---------------- prep_x: x f32 -> xT bf16, xb bf16, S rowsums ----------------
__global__ __launch_bounds__(256) void prep_x(const float* __restrict__ X,
                                              u16* __restrict__ XT,
                                              u16* __restrict__ XB,
                                              float* __restrict__ S) {
  const int b = blockIdx.z;
  const int n0 = blockIdx.x * 64;
  const int c0 = blockIdx.y * 64;
  __shared__ u16 t[64][72];
  const float* Xb = X + (int64_t)b * (512LL * 4096);
  const int tid = threadIdx.x;
  const int r = tid >> 3;        // 0..31
  const int e8 = (tid & 7) * 8;  // 0..56

  // hoist ALL loads (rows r and r+32) before any convert/store: 4 float4 in
  // flight per thread instead of 2 (latency-bound phase).
  const float* p0 = Xb + (int64_t)(c0 + r) * 4096 + n0 + e8;
  const float* p1 = p0 + 32LL * 4096;
  const float4 f0 = *(const float4*)(p0);
  const float4 f1 = *(const float4*)(p0 + 4);
  const float4 h0 = *(const float4*)(p1);
  const float4 h1 = *(const float4*)(p1 + 4);

  union { uint4 q; u16 u[8]; } pa, pb;
  pa.u[0] = f2bf(f0.x); pa.u[1] = f2bf(f0.y); pa.u[2] = f2bf(f0.z); pa.u[3] = f2bf(f0.w);
  pa.u[4] = f2bf(f1.x); pa.u[5] = f2bf(f1.y); pa.u[6] = f2bf(f1.z); pa.u[7] = f2bf(f1.w);
  pb.u[0] = f2bf(h0.x); pb.u[1] = f2bf(h0.y); pb.u[2] = f2bf(h0.z); pb.u[3] = f2bf(h0.w);
  pb.u[4] = f2bf(h1.x); pb.u[5] = f2bf(h1.y); pb.u[6] = f2bf(h1.z); pb.u[7] = f2bf(h1.w);

  const int rowA = r, rowB = r + 32;
  *(uint4*)(XB + ((int64_t)b * 512 + c0 + rowA) * 4096 + n0 + e8) = pa.q;
  *(uint4*)(XB + ((int64_t)b * 512 + c0 + rowB) * 4096 + n0 + e8) = pb.q;
  // XOR-swizzle: logical col c' of row stored at c' ^ (row & 56).
  *(uint4*)&t[rowA][e8 ^ (rowA & 56)] = pa.q;
  *(uint4*)&t[rowB][e8 ^ (rowB & 56)] = pb.q;

  float sa = f0.x + f0.y + f0.z + f0.w + f1.x + f1.y + f1.z + f1.w;
  float sb = h0.x + h0.y + h0.z + h0.w + h1.x + h1.y + h1.z + h1.w;
  sa += __shfl_xor(sa, 1); sa += __shfl_xor(sa, 2); sa += __shfl_xor(sa, 4);
  sb += __shfl_xor(sb, 1); sb += __shfl_xor(sb, 2); sb += __shfl_xor(sb, 4);
  if ((tid & 7) == 0) {
    atomicAdd(&S[b * 512 + c0 + rowA], sa);
    atomicAdd(&S[b * 512 + c0 + rowB], sb);
  }
  __syncthreads();
#pragma unroll
  for (int p = 0; p < 2; p++) {
    const int nr = p * 32 + r;
    union { uint4 q; u16 u[8]; } o;
#pragma unroll
    for (int j = 0; j < 8; j++)
      o.u[j] = t[e8 + j][nr ^ e8];  // (e8+j)&56 == e8 since j<8, e8%8==0
    *(uint4*)(XT + ((int64_t)b * 4096 + n0 + nr) * 512 + c0 + e8) = o.q;
  }
}

// ------- gram, no split-K, BK=64, XCD-swizzled: G_b = XB_b XB_b^T -------
__constant__ const int g_ty[10] = {0,0,0,0,1,1,1,2,2,3};
__constant__ const int g_tx[10] = {0,1,2,3,1,2,3,2,3,3};

__global__ __launch_bounds__(256) void gram_sk(const u16* __restrict__ XB,
                                               u16* __restrict__ G) {
  // bijective XCD swizzle: 160 blocks = 8 XCDs x 20; XCD x owns b = 2x, 2x+1.
  const int flat = blockIdx.x;
  const int w = (flat & 7) * 20 + (flat >> 3);
  const int b = w / 10;
  const int tl = w - b * 10;             // 0..9 upper-triangle tile
  const int m0 = g_ty[tl] * 128, n0 = g_tx[tl] * 128;
  const int tid = threadIdx.x;
  const int lane = tid & 63, wave = tid >> 6;
  __shared__ u16 sA[3][8192];            // 3 bufs x [128][64] bf16 = 48 KB
  __shared__ u16 sB[3][8192];
  const u16* Xb = XB + (int64_t)b * (512LL * 4096);

  f32x4 acc[4][4];
#pragma unroll
  for (int i = 0; i < 4; i++)
#pragma unroll
    for (int j = 0; j < 4; j++)
#pragma unroll
      for (int r = 0; r < 4; r++) acc[i][j][r] = 0.0f;

  const int fr = lane & 15;
  const int hi = lane >> 4;
  // 128B-row bank swizzle: physical chunk p of row r = data chunk p^(r&7).
  const int fkx0 = ((hi) ^ (fr & 7)) * 8;
  const int fkx1 = ((4 + hi) ^ (fr & 7)) * 8;
  const int wm = (wave & 1) * 64, wn = (wave >> 1) * 64;

  const int srow = tid >> 3;             // 0..31
  const int scol = (((tid & 7) ^ ((tid >> 3) & 7))) * 8;
  const u16* ArA = Xb + (int64_t)(m0 + srow) * 4096 + scol;
  const u16* BrA = Xb + (int64_t)(n0 + srow) * 4096 + scol;

  auto stage = [&](int t, int buf) {   // 8 DMAs per tile (BK=64)
    const u16* a = ArA + t * 64;
    const u16* bb = BrA + t * 64;
#pragma unroll
    for (int d = 0; d < 4; d++) {
      gl_lds16(a + (int64_t)d * (32 * 4096), sA[buf] + d * 2048 + tid * 8);
      gl_lds16(bb + (int64_t)d * (32 * 4096), sB[buf] + d * 2048 + tid * 8);
    }
  };
  auto comp = [&](int buf) {
#pragma unroll
    for (int kk = 0; kk < 2; kk++) {
      const int fx = kk ? fkx1 : fkx0;
      frag8 af[4], bf[4];
#pragma unroll
      for (int i = 0; i < 4; i++) {
        af[i] = *(const frag8*)(sA[buf] + (wm + i * 16 + fr) * 64 + fx);
        bf[i] = *(const frag8*)(sB[buf] + (wn + i * 16 + fr) * 64 + fx);
      }
#pragma unroll
      for (int i = 0; i < 4; i++)
#pragma unroll
        for (int j = 0; j < 4; j++)
          acc[i][j] = __builtin_amdgcn_mfma_f32_16x16x32_bf16(af[i], bf[j], acc[i][j], 0, 0, 0);
    }
  };

  stage(0, 0); stage(1, 1);            // NT=64 K-tiles (K=4096, BK=64)
  for (int t = 0; t < 62; t++) {
    SCHED0; SBAR; SCHED0;              // buf[(t+2)%3] free (read at iter t-1)
    stage(t + 2, (t + 2) % 3);
    asm volatile("s_waitcnt vmcnt(16)" ::: "memory");  // tile t landed (16 newer)
    SBAR; SCHED0;                      // cross-wave: all tile-t DMAs landed
    comp(t % 3);
  }
  asm volatile("s_waitcnt vmcnt(0)" ::: "memory");
  SBAR; SCHED0;
  comp(62 % 3); comp(63 % 3);

  u16* Gb = G + (int64_t)b * 262144;
  const int quad = lane >> 4;
#pragma unroll
  for (int i = 0; i < 4; i++)
#pragma unroll
    for (int j = 0; j < 4; j++) {
      const int row0 = m0 + wm + i * 16 + quad * 4;
      const int col = n0 + wn + j * 16 + fr;
      union { u16 u[4]; uint2 v; } mg;
#pragma unroll
      for (int r = 0; r < 4; r++) {
        const u16 h = f2bf(acc[i][j][r]);
        Gb[(int64_t)(row0 + r) * 512 + col] = h;
        mg.u[r] = h;
      }
      if (m0 != n0)  // mirror (4 contiguous bf16 = 8B store)
        *(uint2*)(Gb + (int64_t)col * 512 + row0) = mg.v;
    }
}

// ------ 128x128-tile bt GEMM, K=512, 4 waves, depth-3, XCD-swizzled ------
enum { EPI_BF16 = 0, EPI_SCORES = 1, EPI_BF16I = 2 };

template <int EPI>
__global__ __launch_bounds__(256) void gemm128_bt(
    const u16* __restrict__ A, int64_t sAb, int lda,
    const u16* __restrict__ B, int64_t sBb, int ldb,
    void* __restrict__ Cv, int64_t sCb, int ldc,
    const float* __restrict__ e_bphi, const float* __restrict__ e_btheta,
    const float* __restrict__ e_uphi, const float* __restrict__ e_utheta) {
  // bijective XCD swizzle: 256 = 8 x 32; each XCD owns 2 batches.
  const int flat = blockIdx.x;
  const int w = (flat & 7) * 32 + (flat >> 3);
  const int b = w >> 4;
  const int rem = w & 15;
  const int m0 = (rem >> 2) * 128, n0 = (rem & 3) * 128;
  const int tid = threadIdx.x;
  const int lane = tid & 63, wave = tid >> 6;
  __shared__ u16 sA[4][4096];
  __shared__ u16 sB[4][4096];
  const u16* Ab = A + (int64_t)b * sAb;
  const u16* Bb = B + (int64_t)b * sBb;

  f32x4 acc[4][4];
#pragma unroll
  for (int i = 0; i < 4; i++)
#pragma unroll
    for (int j = 0; j < 4; j++)
#pragma unroll
      for (int r = 0; r < 4; r++) acc[i][j][r] = 0.0f;

  const int srow = tid >> 2;           // 0..63
  const int scol = (((tid & 3) ^ ((tid >> 3) & 3))) * 8;  // pre-swizzled source
  const int fr = lane & 15;
  const int fkx = (((lane >> 4) ^ ((fr >> 1) & 3))) * 8;  // swizzled read chunk
  const int wm = (wave & 1) * 64, wn = (wave >> 1) * 64;

  const u16* Ar0 = Ab + (int64_t)(m0 + srow) * lda + scol;
  const u16* Ar1 = Ab + (int64_t)(m0 + 64 + srow) * lda + scol;
  const u16* Br0 = Bb + (int64_t)(n0 + srow) * ldb + scol;
  const u16* Br1 = Bb + (int64_t)(n0 + 64 + srow) * ldb + scol;

  auto stage = [&](int t, int buf) {   // 4 DMAs per tile
    gl_lds16(Ar0 + t * 32, sA[buf] + tid * 8);
    gl_lds16(Ar1 + t * 32, sA[buf] + 2048 + tid * 8);
    gl_lds16(Br0 + t * 32, sB[buf] + tid * 8);
    gl_lds16(Br1 + t * 32, sB[buf] + 2048 + tid * 8);
  };
  auto comp = [&](int buf) {
    frag8 af[4], bf[4];
#pragma unroll
    for (int i = 0; i < 4; i++) {
      af[i] = *(const frag8*)(sA[buf] + (wm + i * 16 + fr) * 32 + fkx);
      bf[i] = *(const frag8*)(sB[buf] + (wn + i * 16 + fr) * 32 + fkx);
    }
#pragma unroll
    for (int i = 0; i < 4; i++)
#pragma unroll
      for (int j = 0; j < 4; j++)
        acc[i][j] = __builtin_amdgcn_mfma_f32_16x16x32_bf16(af[i], bf[j], acc[i][j], 0, 0, 0);
  };

  stage(0, 0); stage(1, 1); stage(2, 2);   // NT=16 K-tiles, depth-3
#pragma unroll
  for (int t = 0; t < 13; t++) {
    SCHED0; SBAR; SCHED0;              // buf[(t+3)%4] free (read at iter t-1)
    stage(t + 3, (t + 3) % 4);
    asm volatile("s_waitcnt vmcnt(12)" ::: "memory");  // tile t landed (12 newer)
    SBAR; SCHED0;                      // cross-wave visibility
    comp(t % 4);
  }
  asm volatile("s_waitcnt vmcnt(8)" ::: "memory");
  SBAR; SCHED0;
  comp(13 % 4);
  asm volatile("s_waitcnt vmcnt(4)" ::: "memory");
  SBAR; SCHED0;
  comp(14 % 4);
  asm volatile("s_waitcnt vmcnt(0)" ::: "memory");
  SBAR; SCHED0;
  comp(15 % 4);

  const int quad = lane >> 4;
#pragma unroll
  for (int i = 0; i < 4; i++)
#pragma unroll
    for (int j = 0; j < 4; j++)
#pragma unroll
      for (int r = 0; r < 4; r++) {
        const int row = m0 + wm + i * 16 + quad * 4 + r;
        const int col = n0 + wn + j * 16 + fr;
        const float a = acc[i][j][r];
        if constexpr (EPI == EPI_BF16) {
          ((u16*)Cv)[(int64_t)b * sCb + (int64_t)row * ldc + col] = f2bf(a);
        } else if constexpr (EPI == EPI_BF16I) {
          ((u16*)Cv)[(int64_t)b * sCb + (int64_t)row * ldc + col] =
              f2bf(a + (row == col ? 1.0f : 0.0f));
        } else {  // EPI_SCORES
          const float bp = e_bphi[row];
          const float bt = e_btheta[col];
          ((float*)Cv)[(int64_t)b * sCb + (int64_t)row * ldc + col] =
              (a + bp * e_utheta[b * 512 + col] + bt * e_uphi[b * 512 + row] +
               4096.0f * bp * bt) * (1.0f / 512.0f);
        }
      }
}

// ---------------- final: out f32 = (M+I) x + v (A=M bf16, B=xT) ----------------
// 2-buffer, one __syncthreads per iter; bijective XCD swizzle (2048 = 8x256).
__global__ __launch_bounds__(256) void gemm_final(const u16* __restrict__ M,
                                                  const u16* __restrict__ XT,
                                                  const float* __restrict__ V,
                                                  float* __restrict__ O) {
  const int flat = blockIdx.x;
  const int w = (flat & 7) * 256 + (flat >> 3);
  const int b = w >> 7;                  // 2 batches per XCD
  const int rem = w & 127;
  const int m0 = (rem >> 5) * 128;       // 4 m-tiles
  const int n0 = (rem & 31) * 128;       // 32 n-tiles (fastest -> xT sweep)
  const int tid = threadIdx.x;
  const int lane = tid & 63, wave = tid >> 6;
  __shared__ u16 sA[2][4096];
  __shared__ u16 sB[2][4096];
  const u16* Ab = M + (int64_t)b * 262144;
  const u16* Bb = XT + (int64_t)b * (4096LL * 512);

  f32x4 acc[4][4];
#pragma unroll
  for (int i = 0; i < 4; i++)
#pragma unroll
    for (int j = 0; j < 4; j++)
#pragma unroll
      for (int r = 0; r < 4; r++) acc[i][j][r] = 0.0f;

  const int srow = tid >> 2;
  const int scol = (((tid & 3) ^ ((tid >> 3) & 3))) * 8;  // pre-swizzled source
  const int fr = lane & 15;
  const int fkx = (((lane >> 4) ^ ((fr >> 1) & 3))) * 8;  // swizzled read chunk
  const int wm = (wave & 1) * 64, wn = (wave >> 1) * 64;

  const u16* Ar0 = Ab + (int64_t)(m0 + srow) * 512 + scol;
  const u16* Ar1 = Ab + (int64_t)(m0 + 64 + srow) * 512 + scol;
  const u16* Br0 = Bb + (int64_t)(n0 + srow) * 512 + scol;
  const u16* Br1 = Bb + (int64_t)(n0 + 64 + srow) * 512 + scol;

  // prologue
  gl_lds16(Ar0, sA[0] + tid * 8);
  gl_lds16(Ar1, sA[0] + 2048 + tid * 8);
  gl_lds16(Br0, sB[0] + tid * 8);
  gl_lds16(Br1, sB[0] + 2048 + tid * 8);
  __syncthreads();

  for (int k0 = 0; k0 < 512; k0 += 32) {
    const int cur = (k0 >> 5) & 1;
    if (k0 + 32 < 512) {
      u16* dA = sA[cur ^ 1];
      u16* dB = sB[cur ^ 1];
      gl_lds16(Ar0 + k0 + 32, dA + tid * 8);
      gl_lds16(Ar1 + k0 + 32, dA + 2048 + tid * 8);
      gl_lds16(Br0 + k0 + 32, dB + tid * 8);
      gl_lds16(Br1 + k0 + 32, dB + 2048 + tid * 8);
    }
    frag8 af[4], bf[4];
#pragma unroll
    for (int i = 0; i < 4; i++) {
      af[i] = *(const frag8*)(sA[cur] + (wm + i * 16 + fr) * 32 + fkx);
      bf[i] = *(const frag8*)(sB[cur] + (wn + i * 16 + fr) * 32 + fkx);
    }
#pragma unroll
    for (int i = 0; i < 4; i++)
#pragma unroll
      for (int j = 0; j < 4; j++)
        acc[i][j] = __builtin_amdgcn_mfma_f32_16x16x32_bf16(af[i], bf[j], acc[i][j], 0, 0, 0);
    __syncthreads();
  }

  const int quad = lane >> 4;
#pragma unroll
  for (int i = 0; i < 4; i++)
#pragma unroll
    for (int j = 0; j < 4; j++)
#pragma unroll
      for (int r = 0; r < 4; r++) {
        const int row = m0 + wm + i * 16 + quad * 4 + r;
        const int col = n0 + wn + j * 16 + fr;
        O[(int64_t)b * (512LL * 4096) + (int64_t)row * 4096 + col] =
            acc[i][j][r] + V[b * 512 + row];
      }
}

// ---------------- small helpers ----------------
// uv: grid (16, 8), 256 threads; 4 lanes per output row, shfl reduce.
__global__ __launch_bounds__(256) void uv_kernel(const float* __restrict__ Wphi,
                                                 const float* __restrict__ Wtheta,
                                                 const float* __restrict__ S,
                                                 float* __restrict__ UPH, float* __restrict__ UTH) {
  const int b = blockIdx.x;
  const int o0 = blockIdx.y * 64;
  const int tid = threadIdx.x;
  __shared__ float s[512];
  s[tid] = S[b * 512 + tid];
  s[tid + 256] = S[b * 512 + tid + 256];
  __syncthreads();
  const int o = o0 + (tid >> 2);
  const int q = tid & 3;
  float a0 = 0.f, a1 = 0.f;
  for (int c = q * 128; c < q * 128 + 128; c += 4) {
    const float4 wa = *(const float4*)(Wphi + (int64_t)o * 512 + c);
    const float4 wb = *(const float4*)(Wtheta + (int64_t)o * 512 + c);
    a0 += wa.x * s[c] + wa.y * s[c + 1] + wa.z * s[c + 2] + wa.w * s[c + 3];
    a1 += wb.x * s[c] + wb.y * s[c + 1] + wb.z * s[c + 2] + wb.w * s[c + 3];
  }
  a0 += __shfl_xor(a0, 1); a0 += __shfl_xor(a0, 2);
  a1 += __shfl_xor(a1, 1); a1 += __shfl_xor(a1, 2);
  if (q == 0) {
    UPH[b * 512 + o] = a0;
    UTH[b * 512 + o] = a1;
  }
}

// v: grid (16, 8), same structure.
__global__ __launch_bounds__(256) void v_kernel(const float* __restrict__ Wout,
                                                const float* __restrict__ R,
                                                const float* __restrict__ bout,
                                                float* __restrict__ V) {
  const int b = blockIdx.x;
  const int o0 = blockIdx.y * 64;
  const int tid = threadIdx.x;
  __shared__ float s[512];
  s[tid] = R[b * 512 + tid];
  s[tid + 256] = R[b * 512 + tid + 256];
  __syncthreads();
  const int o = o0 + (tid >> 2);
  const int q = tid & 3;
  float a0 = 0.f;
  for (int c = q * 128; c < q * 128 + 128; c += 4) {
    const float4 wa = *(const float4*)(Wout + (int64_t)o * 512 + c);
    a0 += wa.x * s[c] + wa.y * s[c + 1] + wa.z * s[c + 2] + wa.w * s[c + 3];
  }
  a0 += __shfl_xor(a0, 1); a0 += __shfl_xor(a0, 2);
  if (q == 0) V[b * 512 + o] = a0 + bout[o];
}

__global__ __launch_bounds__(256) void convert_w(const float* __restrict__ W0,
                                                 const float* __restrict__ W1,
                                                 const float* __restrict__ W2,
                                                 u16* __restrict__ O0, u16* __restrict__ O1,
                                                 u16* __restrict__ O2) {
  const int idx = blockIdx.x * 256 + threadIdx.x;
  const int m = idx >> 16;
  const int off = (idx & 65535) * 4;
  const float* src = (m == 0) ? W0 : (m == 1) ? W1 : W2;
  u16* dst = (m == 0) ? O0 : (m == 1) ? O1 : O2;
  const float4 f = *(const float4*)(src + off);
  union { u16 u[4]; uint2 v; } p;
  p.u[0] = f2bf(f.x); p.u[1] = f2bf(f.y); p.u[2] = f2bf(f.z); p.u[3] = f2bf(f.w);
  *(uint2*)(dst + off) = p.v;
}

__global__ void wg_transpose(const float* __restrict__ Wg, u16* __restrict__ WgT) {
  __shared__ float t[16][17];
  const int i0 = blockIdx.y * 16, j0 = blockIdx.x * 16;
  t[threadIdx.y][threadIdx.x] = Wg[(i0 + threadIdx.y) * 512 + j0 + threadIdx.x];
  __syncthreads();
  WgT[(j0 + threadIdx.y) * 512 + i0 + threadIdx.x] = f2bf(t[threadIdx.x][threadIdx.y]);
}

__global__ __launch_bounds__(64) void softmax_k(float* __restrict__ SC,
                                                const float* __restrict__ bg,
                                                float* __restrict__ R) {
  const int row = blockIdx.x;
  const int lane = threadIdx.x;
  float* Sr = SC + (int64_t)row * 512;
  union { float4 q[2]; float v[8]; } u;
  u.q[0] = *(const float4*)(Sr + lane * 8);
  u.q[1] = *(const float4*)(Sr + lane * 8 + 4);
  const float4 g0 = *(const float4*)(bg + lane * 8);
  const float4 g1 = *(const float4*)(bg + lane * 8 + 4);
  const float gb[8] = { g0.x, g0.y, g0.z, g0.w, g1.x, g1.y, g1.z, g1.w };
  float m = u.v[0];
#pragma unroll
  for (int j = 1; j < 8; j++) m = fmaxf(m, u.v[j]);
#pragma unroll
  for (int off = 32; off > 0; off >>= 1) m = fmaxf(m, __shfl_xor(m, off));
  float e[8], s = 0.f, sb = 0.f;
#pragma unroll
  for (int j = 0; j < 8; j++) {
    e[j] = __expf(u.v[j] - m);
    s += e[j];
    sb += e[j] * gb[j];
  }
#pragma unroll
  for (int off = 32; off > 0; off >>= 1) { s += __shfl_xor(s, off); sb += __shfl_xor(sb, off); }
  const float inv = 1.0f / s;
  union { uint4 q; u16 h[8]; } o;
#pragma unroll
  for (int j = 0; j < 8; j++) o.h[j] = f2bf(e[j] * inv);
  *(uint4*)((u16*)SC + (int64_t)row * 1024 + lane * 8) = o.q;  // attn in-place
  if (lane == 0) R[row] = sb * inv;
}

extern "C" void kernel_launch(void* const* d_in, const int* in_sizes, int n_in,
                              void* d_out, int out_size, void* d_ws, size_t ws_size,
                              hipStream_t stream) {
  const float* x      = (const float*)d_in[0];
  const float* Wtheta = (const float*)d_in[1];
  const float* btheta = (const float*)d_in[2];
  const float* Wphi   = (const float*)d_in[3];
  const float* bphi   = (const float*)d_in[4];
  const float* Wg     = (const float*)d_in[5];
  const float* bg     = (const float*)d_in[6];
  const float* Wout   = (const float*)d_in[7];
  const float* bout   = (const float*)d_in[8];

  char* ws = (char*)d_ws;                   // ~98.1 MiB (same as proven R3 budget)
  u16*   xT     = (u16*)(ws + 0);           // 67,108,864
  u16*   G      = (u16*)(ws + 67108864);    //  8,388,608
  u16*   T1     = (u16*)(ws + 75497472);    //  8,388,608
  float* SC     = (float*)(ws + 83886080);  // 16,777,216 (attn bf16 in-place)
  u16*   Wphib  = (u16*)(ws + 100663296);
  u16*   Wthetab= (u16*)(ws + 101187584);
  u16*   Woutb  = (u16*)(ws + 101711872);
  u16*   WgTb   = (u16*)(ws + 102236160);
  float* S      = (float*)(ws + 102760448);
  float* UPH    = (float*)(ws + 102793216);
  float* UTH    = (float*)(ws + 102825984);
  float* R      = (float*)(ws + 102858752);
  float* V      = (float*)(ws + 102891520);
  u16* ATT = (u16*)SC;  // bf16 attn, row stride 1024 u16
  u16* Q = G;           // G dead after T1-gemm
  u16* M = T1;          // T1 dead after scores-gemm

  // d_out (134,217,728 B) as mid-pipeline scratch; fully overwritten by gemm_final.
  u16*   XB = (u16*)d_out;                          // 67,108,864: bf16 x

  hipMemsetAsync(S, 0, 32768, stream);
  prep_x<<<dim3(64, 8, 16), 256, 0, stream>>>(x, xT, XB, S);
  uv_kernel<<<dim3(16, 8), 256, 0, stream>>>(Wphi, Wtheta, S, UPH, UTH);
  convert_w<<<768, 256, 0, stream>>>(Wphi, Wtheta, Wout, Wphib, Wthetab, Woutb);
  wg_transpose<<<dim3(32, 32), dim3(16, 16), 0, stream>>>(Wg, WgTb);
  // G_b = XB_b XB_b^T directly in bf16 (no split-K partials, no reduce)
  gram_sk<<<dim3(160), 256, 0, stream>>>(XB, G);
  // T1_b = Wphi G_b (G symmetric -> bt form valid)
  gemm128_bt<EPI_BF16><<<dim3(256), 256, 0, stream>>>(
      Wphib, 0, 512, G, 512LL * 512, 512, T1, 512LL * 512, 512,
      nullptr, nullptr, nullptr, nullptr);
  // scores_b = (T1 Wtheta^T + rank-1 terms) / 512
  gemm128_bt<EPI_SCORES><<<dim3(256), 256, 0, stream>>>(
      T1, 512LL * 512, 512, Wthetab, 0, 512, SC, 512LL * 512, 512,
      bphi, btheta, UPH, UTH);
  softmax_k<<<8192, 64, 0, stream>>>(SC, bg, R);
  // Q_b[j,c] = sum_d WgT[j,d] attn[c,d]
  gemm128_bt<EPI_BF16><<<dim3(256), 256, 0, stream>>>(
      WgTb, 0, 512, ATT, 512LL * 1024, 1024, Q, 512LL * 512, 512,
      nullptr, nullptr, nullptr, nullptr);
  // M_b = Wout Q (+ I fold for the residual)
  gemm128_bt<EPI_BF16I><<<dim3(256), 256, 0, stream>>>(
      Woutb, 0, 512, Q, 512LL * 512, 512, M, 512LL * 512, 512,
      nullptr, nullptr, nullptr, nullptr);
  v_kernel<<<dim3(16, 8), 256, 0, stream>>>(Wout, R, bout, V);
  // out = (M+I) x + v  (reads xT + M only; overwrites all of d_out)
  gemm_final<<<dim3(2048), 256, 0, stream>>>(M, xT, V, (float*)d_out);
}